// Round 1
// baseline (436.173 us; speedup 1.0000x reference)
//
#include <hip/hip_runtime.h>
#include <math.h>

#define N_ANCH 87296
#define NCLS 91
#define NBINS 8192
#define K_CAND 256
#define CAP 1024
#define MAX_OUT 100
#define IOU_TH 0.6f

// ws layout (bytes):
//      0: hist            (NBINS*4 = 32768)
//  32768: counter         (4)
//  32772: found_bin       (4)
//  32784: cand_score      (CAP*4   = 4096)
//  36880: cand_box        (CAP*16  = 16384)   (16B aligned: 36880 = 16*2305)
//  53264: cand_label      (CAP*4   = 4096)
//  57360: scores_all      (N_ANCH*4 = 349184)

__device__ __forceinline__ float sigmoidf_(float x) {
    return 1.0f / (1.0f + expf(-x));
}

// Kernel A: per-anchor score (max over 91 logits) + histogram
__global__ void score_kernel(const float* __restrict__ logits,
                             const float* __restrict__ ctr,
                             float* __restrict__ scores,
                             unsigned* __restrict__ hist) {
    int i = blockIdx.x * blockDim.x + threadIdx.x;
    if (i >= N_ANCH) return;
    const float* row = logits + (long)i * NCLS;
    float m = row[0];
    #pragma unroll
    for (int j = 1; j < NCLS; ++j) m = fmaxf(m, row[j]);
    float s = sqrtf(sigmoidf_(m) * sigmoidf_(ctr[i]));
    scores[i] = s;
    int b = (int)(s * (float)NBINS);
    b = min(max(b, 0), NBINS - 1);
    atomicAdd(&hist[b], 1u);
}

// Kernel B: single wave scans histogram from the top to find the threshold bin
__global__ void thresh_kernel(const unsigned* __restrict__ hist,
                              int* __restrict__ found_bin) {
    int lane = threadIdx.x;
    unsigned total = 0;
    int fb = 0;
    for (int chunk = 0; chunk < NBINS / 64; ++chunk) {
        int bin = NBINS - 1 - chunk * 64 - lane;   // lane 0 = highest bin
        unsigned c = hist[bin];
        // inclusive prefix sum over lanes (descending-bin order)
        unsigned p = c;
        #pragma unroll
        for (int d = 1; d < 64; d <<= 1) {
            unsigned t = (unsigned)__shfl_up((int)p, d, 64);
            if (lane >= d) p += t;
        }
        unsigned chunkSum = (unsigned)__shfl((int)p, 63, 64);
        if (total + chunkSum >= K_CAND) {
            bool hit = (total + p >= K_CAND);
            unsigned long long mask = __ballot(hit);
            int L = __ffsll((long long)mask) - 1;   // first lane reaching K
            fb = NBINS - 1 - chunk * 64 - L;
            break;
        }
        total += chunkSum;
    }
    if (lane == 0) *found_bin = fb;
}

// Kernel C: compact candidates >= threshold bin; recompute label + decode box
__global__ void compact_kernel(const float* __restrict__ logits,
                               const float* __restrict__ boxreg,
                               const float* __restrict__ anchors,
                               const float* __restrict__ scores,
                               const int* __restrict__ found_bin,
                               unsigned* __restrict__ counter,
                               float* __restrict__ cscore,
                               float4* __restrict__ cbox,
                               int* __restrict__ clabel) {
    int i = blockIdx.x * blockDim.x + threadIdx.x;
    if (i >= N_ANCH) return;
    float s = scores[i];
    int b = (int)(s * (float)NBINS);
    b = min(max(b, 0), NBINS - 1);
    if (b < *found_bin) return;
    unsigned pos = atomicAdd(counter, 1u);
    if (pos >= CAP) return;

    // label = argmax of logits row (first max wins, matching jnp.argmax)
    const float* row = logits + (long)i * NCLS;
    float m = row[0];
    int lab = 0;
    #pragma unroll
    for (int j = 1; j < NCLS; ++j) {
        float v = row[j];
        if (v > m) { m = v; lab = j; }
    }

    // decode box
    float a0 = anchors[i * 4 + 0], a1 = anchors[i * 4 + 1];
    float a2 = anchors[i * 4 + 2], a3 = anchors[i * 4 + 3];
    float cx = 0.5f * (a0 + a2);
    float cy = 0.5f * (a1 + a3);
    float w  = a2 - a0;
    float h  = a3 - a1;
    float r0 = boxreg[i * 4 + 0], r1 = boxreg[i * 4 + 1];
    float r2 = boxreg[i * 4 + 2], r3 = boxreg[i * 4 + 3];
    float4 bb;
    bb.x = cx - r0 * w;
    bb.y = cy - r1 * h;
    bb.z = cx + r2 * w;
    bb.w = cy + r3 * h;

    cscore[pos] = s;
    cbox[pos]   = bb;
    clabel[pos] = lab;
}

// Kernel D: single-wave greedy NMS over candidates, all state in registers.
__global__ void nms_kernel(const unsigned* __restrict__ counter,
                           const float* __restrict__ cscore,
                           const float4* __restrict__ cbox,
                           const int* __restrict__ clabel,
                           float* __restrict__ out) {
    const int lane = threadIdx.x;
    int M = (int)min(*counter, (unsigned)CAP);

    const int SLOTS = CAP / 64;  // 16
    float sc[SLOTS], x1[SLOTS], y1[SLOTS], x2[SLOTS], y2[SLOTS], ar[SLOTS];
    int lab[SLOTS];
    #pragma unroll
    for (int s = 0; s < SLOTS; ++s) {
        int idx = s * 64 + lane;
        if (idx < M) {
            sc[s] = cscore[idx];
            float4 b = cbox[idx];
            x1[s] = b.x; y1[s] = b.y; x2[s] = b.z; y2[s] = b.w;
            ar[s] = fmaxf(b.z - b.x, 0.0f) * fmaxf(b.w - b.y, 0.0f);
            lab[s] = clabel[idx];
        } else {
            sc[s] = -INFINITY;
            x1[s] = y1[s] = x2[s] = y2[s] = 0.0f;
            ar[s] = 0.0f;
            lab[s] = 0;
        }
    }

    for (int it = 0; it < MAX_OUT; ++it) {
        // local argmax across register slots
        float best = -INFINITY;
        int bslot = 0;
        #pragma unroll
        for (int s = 0; s < SLOTS; ++s) {
            if (sc[s] > best) { best = sc[s]; bslot = s; }
        }
        int pid = (bslot << 6) | lane;
        // wave argmax (scores are distinct -> deterministic)
        #pragma unroll
        for (int d = 32; d >= 1; d >>= 1) {
            float ob = __shfl_xor(best, d, 64);
            int   op = __shfl_xor(pid, d, 64);
            if (ob > best) { best = ob; pid = op; }
        }
        int wlane = pid & 63;
        int wslot = pid >> 6;

        // gather the selected box (wslot is wave-uniform; static-index select)
        float sx1 = 0.f, sy1 = 0.f, sx2 = 0.f, sy2 = 0.f, sar = 0.f;
        int slab = 0;
        #pragma unroll
        for (int s = 0; s < SLOTS; ++s) {
            if (s == wslot) {
                sx1 = x1[s]; sy1 = y1[s]; sx2 = x2[s]; sy2 = y2[s];
                sar = ar[s]; slab = lab[s];
            }
        }
        sx1 = __shfl(sx1, wlane, 64);
        sy1 = __shfl(sy1, wlane, 64);
        sx2 = __shfl(sx2, wlane, 64);
        sy2 = __shfl(sy2, wlane, 64);
        sar = __shfl(sar, wlane, 64);
        slab = __shfl(slab, wlane, 64);

        if (lane == 0) {
            out[it * 4 + 0] = sx1;
            out[it * 4 + 1] = sy1;
            out[it * 4 + 2] = sx2;
            out[it * 4 + 3] = sy2;
            out[4 * MAX_OUT + it] = (float)slab;       // labels as float values
            out[5 * MAX_OUT + it] = best;              // max score
        }

        // suppression: IEEE semantics must match the reference (0/0 = NaN,
        // NaN > 0.6 is false -> zero-area selected box suppresses nothing,
        // including itself -> selection "locks", same as jnp reference).
        #pragma unroll
        for (int s = 0; s < SLOTS; ++s) {
            float ix1 = fmaxf(sx1, x1[s]);
            float iy1 = fmaxf(sy1, y1[s]);
            float ix2 = fminf(sx2, x2[s]);
            float iy2 = fminf(sy2, y2[s]);
            float inter = fmaxf(ix2 - ix1, 0.0f) * fmaxf(iy2 - iy1, 0.0f);
            float iou = inter / (sar + ar[s] - inter);
            if (iou > IOU_TH) sc[s] = -INFINITY;
        }
    }
}

extern "C" void kernel_launch(void* const* d_in, const int* in_sizes, int n_in,
                              void* d_out, int out_size, void* d_ws, size_t ws_size,
                              hipStream_t stream) {
    const float* logits  = (const float*)d_in[0];
    const float* boxreg  = (const float*)d_in[1];
    const float* ctr     = (const float*)d_in[2];
    const float* anchors = (const float*)d_in[3];
    float* out = (float*)d_out;

    char* ws = (char*)d_ws;
    unsigned* hist    = (unsigned*)(ws + 0);
    unsigned* counter = (unsigned*)(ws + 32768);
    int* found_bin    = (int*)(ws + 32772);
    float* cscore     = (float*)(ws + 32784);
    float4* cbox      = (float4*)(ws + 36880);
    int* clabel       = (int*)(ws + 53264);
    float* scores     = (float*)(ws + 57360);

    // zero hist + counter
    hipMemsetAsync(ws, 0, 32772, stream);

    int blocks = (N_ANCH + 255) / 256;
    score_kernel<<<blocks, 256, 0, stream>>>(logits, ctr, scores, hist);
    thresh_kernel<<<1, 64, 0, stream>>>(hist, found_bin);
    compact_kernel<<<blocks, 256, 0, stream>>>(logits, boxreg, anchors, scores,
                                               found_bin, counter, cscore, cbox, clabel);
    nms_kernel<<<1, 64, 0, stream>>>(counter, cscore, cbox, clabel, out);
}

// Round 2
// 39.446 us; speedup vs baseline: 11.0574x; 11.0574x over previous
//
#include <hip/hip_runtime.h>
#include <math.h>

#define N_ANCH 87296
#define NCLS 91
#define NBINS 8192
#define K_CAND 256
#define CAP 512
#define MAX_OUT 100
#define IOU_TH 0.6f

// ws layout (bytes):
//      0: hist            (NBINS*4 = 32768)
//  32768: counter         (4)
//  32772: found_bin       (4)
//  32784: cand_score      (CAP*4  = 2048)
//  34832: cand_box        (CAP*16 = 8192)   (34832 % 16 == 0)
//  43024: cand_label      (CAP*4  = 2048)
//  45072: scores_all      (N_ANCH*4 = 349184)

__device__ __forceinline__ float sigmoidf_(float x) {
    return 1.0f / (1.0f + expf(-x));
}

// Kernel A: per-anchor score (max over 91 logits) + histogram
__global__ void score_kernel(const float* __restrict__ logits,
                             const float* __restrict__ ctr,
                             float* __restrict__ scores,
                             unsigned* __restrict__ hist) {
    int i = blockIdx.x * blockDim.x + threadIdx.x;
    if (i >= N_ANCH) return;
    const float* row = logits + (long)i * NCLS;
    float m = row[0];
    #pragma unroll
    for (int j = 1; j < NCLS; ++j) m = fmaxf(m, row[j]);
    float s = sqrtf(sigmoidf_(m) * sigmoidf_(ctr[i]));
    scores[i] = s;
    int b = (int)(s * (float)NBINS);
    b = min(max(b, 0), NBINS - 1);
    atomicAdd(&hist[b], 1u);
}

// Kernel B: single wave scans histogram from the top to find the threshold bin
__global__ void thresh_kernel(const unsigned* __restrict__ hist,
                              int* __restrict__ found_bin) {
    int lane = threadIdx.x;
    unsigned total = 0;
    int fb = 0;
    for (int chunk = 0; chunk < NBINS / 64; ++chunk) {
        int bin = NBINS - 1 - chunk * 64 - lane;   // lane 0 = highest bin
        unsigned c = hist[bin];
        unsigned p = c;
        #pragma unroll
        for (int d = 1; d < 64; d <<= 1) {
            unsigned t = (unsigned)__shfl_up((int)p, d, 64);
            if (lane >= d) p += t;
        }
        unsigned chunkSum = (unsigned)__shfl((int)p, 63, 64);
        if (total + chunkSum >= K_CAND) {
            bool hit = (total + p >= K_CAND);
            unsigned long long mask = __ballot(hit);
            int L = __ffsll((long long)mask) - 1;
            fb = NBINS - 1 - chunk * 64 - L;
            break;
        }
        total += chunkSum;
    }
    if (lane == 0) *found_bin = fb;
}

// Kernel C: compact candidates >= threshold bin; recompute label + decode box
__global__ void compact_kernel(const float* __restrict__ logits,
                               const float* __restrict__ boxreg,
                               const float* __restrict__ anchors,
                               const float* __restrict__ scores,
                               const int* __restrict__ found_bin,
                               unsigned* __restrict__ counter,
                               float* __restrict__ cscore,
                               float4* __restrict__ cbox,
                               int* __restrict__ clabel) {
    int i = blockIdx.x * blockDim.x + threadIdx.x;
    if (i >= N_ANCH) return;
    float s = scores[i];
    int b = (int)(s * (float)NBINS);
    b = min(max(b, 0), NBINS - 1);
    if (b < *found_bin) return;
    unsigned pos = atomicAdd(counter, 1u);
    if (pos >= CAP) return;

    const float* row = logits + (long)i * NCLS;
    float m = row[0];
    int lab = 0;
    #pragma unroll
    for (int j = 1; j < NCLS; ++j) {
        float v = row[j];
        if (v > m) { m = v; lab = j; }
    }

    float a0 = anchors[i * 4 + 0], a1 = anchors[i * 4 + 1];
    float a2 = anchors[i * 4 + 2], a3 = anchors[i * 4 + 3];
    float cx = 0.5f * (a0 + a2);
    float cy = 0.5f * (a1 + a3);
    float w  = a2 - a0;
    float h  = a3 - a1;
    float r0 = boxreg[i * 4 + 0], r1 = boxreg[i * 4 + 1];
    float r2 = boxreg[i * 4 + 2], r3 = boxreg[i * 4 + 3];
    float4 bb;
    bb.x = cx - r0 * w;
    bb.y = cy - r1 * h;
    bb.z = cx + r2 * w;
    bb.w = cy + r3 * h;

    cscore[pos] = s;
    cbox[pos]   = bb;
    clabel[pos] = lab;
}

// Kernel D: greedy NMS, one candidate per thread (512 threads = 8 waves).
// All candidate state lives in 7 scalar registers per thread — no arrays,
// no spill. Cross-wave argmax via LDS. Zero-area winner => reference "locks"
// (0/0=NaN suppresses nothing incl. itself) => fill remaining outputs, exit.
__global__ void nms_kernel(const unsigned* __restrict__ counter,
                           const float* __restrict__ cscore,
                           const float4* __restrict__ cbox,
                           const int* __restrict__ clabel,
                           float* __restrict__ out) {
    __shared__ float s_best[8];
    __shared__ int   s_bid[8];
    __shared__ float s_box[5];   // x1,y1,x2,y2,area
    __shared__ int   s_lab;

    const int tid  = threadIdx.x;
    const int lane = tid & 63;
    const int wid  = tid >> 6;
    int M = (int)min(*counter, (unsigned)CAP);

    float sc, X1, Y1, X2, Y2, AR;
    int LAB;
    if (tid < M) {
        sc = cscore[tid];
        float4 b = cbox[tid];
        X1 = b.x; Y1 = b.y; X2 = b.z; Y2 = b.w;
        AR = fmaxf(b.z - b.x, 0.0f) * fmaxf(b.w - b.y, 0.0f);
        LAB = clabel[tid];
    } else {
        sc = -INFINITY;
        X1 = Y1 = X2 = Y2 = AR = 0.0f;
        LAB = 0;
    }

    for (int it = 0; it < MAX_OUT; ++it) {
        // intra-wave argmax (butterfly)
        float b = sc;
        int id = tid;
        #pragma unroll
        for (int d = 32; d >= 1; d >>= 1) {
            float ob = __shfl_xor(b, d, 64);
            int   oid = __shfl_xor(id, d, 64);
            if (ob > b) { b = ob; id = oid; }
        }
        if (lane == 0) { s_best[wid] = b; s_bid[wid] = id; }
        __syncthreads();
        // every thread reduces the 8 per-wave results
        float gb = s_best[0];
        int gid = s_bid[0];
        #pragma unroll
        for (int w = 1; w < 8; ++w) {
            if (s_best[w] > gb) { gb = s_best[w]; gid = s_bid[w]; }
        }
        // winner publishes its box
        if (tid == gid) {
            s_box[0] = X1; s_box[1] = Y1; s_box[2] = X2; s_box[3] = Y2;
            s_box[4] = AR; s_lab = LAB;
        }
        __syncthreads();
        float sx1 = s_box[0], sy1 = s_box[1], sx2 = s_box[2], sy2 = s_box[3];
        float sar = s_box[4];
        int   slab = s_lab;

        if (tid == 0) {
            out[it * 4 + 0] = sx1;
            out[it * 4 + 1] = sy1;
            out[it * 4 + 2] = sx2;
            out[it * 4 + 3] = sy2;
            out[4 * MAX_OUT + it] = (float)slab;
            out[5 * MAX_OUT + it] = gb;
        }

        // Lock: zero-area winner has inter==0 with every box (x2<=x1 or
        // y2<=y1 kills the clamped intersection), so iou is 0 or NaN for
        // all boxes and 0/0=NaN for itself -> nothing suppressed -> the
        // reference re-selects this same box for every remaining slot.
        if (sar == 0.0f) {
            for (int r = it + 1 + tid; r < MAX_OUT; r += blockDim.x) {
                out[r * 4 + 0] = sx1;
                out[r * 4 + 1] = sy1;
                out[r * 4 + 2] = sx2;
                out[r * 4 + 3] = sy2;
                out[4 * MAX_OUT + r] = (float)slab;
                out[5 * MAX_OUT + r] = gb;
            }
            return;
        }

        // suppress (winner suppresses itself: iou = 1 > 0.6)
        float ix1 = fmaxf(sx1, X1);
        float iy1 = fmaxf(sy1, Y1);
        float ix2 = fminf(sx2, X2);
        float iy2 = fminf(sy2, Y2);
        float inter = fmaxf(ix2 - ix1, 0.0f) * fmaxf(iy2 - iy1, 0.0f);
        float iou = inter / (sar + AR - inter);
        if (iou > IOU_TH) sc = -INFINITY;
        __syncthreads();
    }
}

extern "C" void kernel_launch(void* const* d_in, const int* in_sizes, int n_in,
                              void* d_out, int out_size, void* d_ws, size_t ws_size,
                              hipStream_t stream) {
    const float* logits  = (const float*)d_in[0];
    const float* boxreg  = (const float*)d_in[1];
    const float* ctr     = (const float*)d_in[2];
    const float* anchors = (const float*)d_in[3];
    float* out = (float*)d_out;

    char* ws = (char*)d_ws;
    unsigned* hist    = (unsigned*)(ws + 0);
    unsigned* counter = (unsigned*)(ws + 32768);
    int* found_bin    = (int*)(ws + 32772);
    float* cscore     = (float*)(ws + 32784);
    float4* cbox      = (float4*)(ws + 34832);
    int* clabel       = (int*)(ws + 43024);
    float* scores     = (float*)(ws + 45072);

    hipMemsetAsync(ws, 0, 32772, stream);

    int blocks = (N_ANCH + 255) / 256;
    score_kernel<<<blocks, 256, 0, stream>>>(logits, ctr, scores, hist);
    thresh_kernel<<<1, 64, 0, stream>>>(hist, found_bin);
    compact_kernel<<<blocks, 256, 0, stream>>>(logits, boxreg, anchors, scores,
                                               found_bin, counter, cscore, cbox, clabel);
    nms_kernel<<<1, 512, 0, stream>>>(counter, cscore, cbox, clabel, out);
}